// Round 4
// baseline (379.023 us; speedup 1.0000x reference)
//
#include <hip/hip_runtime.h>
#include <math.h>

#define B_BAGS 8
#define N_INST 8192
#define D_DIM  512
#define H_ATT  64
#define TOPK_K 2457
#define ROWS_TOTAL (B_BAGS * N_INST)

typedef __attribute__((ext_vector_type(8))) short bf16x8;
typedef __attribute__((ext_vector_type(4))) float f32x4;
typedef __attribute__((ext_vector_type(4))) unsigned short u16x4;

// ---- workspace layout (bytes) ----
#define WS_W1T_HI 0                          // [64][512] bf16 bits
#define WS_W1T_LO 65536                      // [64][512] bf16 bits
#define WS_META   131072                     // 8 uint T, 8 int Icut, 2 uint counters
#define WS_PART3  131584                     // [8][64][512] f32 gather partials (1 MB)
#define WS_PART1  (WS_PART3 + 8*64*512*4)    // [8kt][8b][512] f32 layer1 partials
#define WS_PART2  (WS_PART1 + 8*8*512*4)     // [8kt][8b][512] f32 layer2 partials

__device__ __forceinline__ unsigned short bf16_rn(float f) {
  unsigned int x = __float_as_uint(f);
  unsigned int r = (x + 0x7FFFu + ((x >> 16) & 1u)) >> 16;
  return (unsigned short)r;
}
__device__ __forceinline__ float bf16_f(unsigned short u) {
  return __uint_as_float(((unsigned int)u) << 16);
}
__device__ __forceinline__ float gelu_f(float v) {
  float u = 0.7978845608028654f * (v + 0.044715f * v * v * v);
  return 0.5f * v * (1.0f + tanhf(u));
}

// ---------------- kernel 0: transpose + hi/lo split of aW1; zero counters ----
__global__ __launch_bounds__(256) void k_prep(const float* __restrict__ aW1,
                                              unsigned short* __restrict__ hi,
                                              unsigned short* __restrict__ lo,
                                              unsigned int* __restrict__ counters) {
  if (blockIdx.x == 0 && threadIdx.x < 4) counters[threadIdx.x] = 0u;
  int o = blockIdx.x * 256 + threadIdx.x;   // over 64*512 outputs, layout [n][k]
  if (o >= H_ATT * D_DIM) return;
  int n = o >> 9;
  int k = o & 511;
  float v = aW1[k * H_ATT + n];
  unsigned short h = bf16_rn(v);
  unsigned short l = bf16_rn(v - bf16_f(h));
  hi[o] = h;
  lo[o] = l;
}

// ---------------- kernel 1: score MLP -> sigmoid weights, + fused top-k tail ----
#define BM 128
#define BK 64
#define LDK 72   // padded LDS k-stride (bf16 elems)

__global__ __launch_bounds__(256, 2) void k_scores(
    const float* __restrict__ x,
    const unsigned short* __restrict__ w1t_hi,
    const unsigned short* __restrict__ w1t_lo,
    const float* __restrict__ ab1, const float* __restrict__ aW2,
    const float* __restrict__ ab2, float* __restrict__ wout,
    unsigned int* __restrict__ meta, unsigned int* __restrict__ counters) {
  __shared__ unsigned short A_hi[BM * LDK];
  __shared__ unsigned short A_lo[BM * LDK];
  __shared__ unsigned short Bh[H_ATT * LDK];
  __shared__ unsigned short Bl[H_ATT * LDK];
  __shared__ unsigned int rank_s;

  int tid = threadIdx.x;
  int wave = tid >> 6, lane = tid & 63;
  int rowBase = blockIdx.x * BM;

  f32x4 acc[2][4];
#pragma unroll
  for (int s = 0; s < 2; s++)
#pragma unroll
    for (int t = 0; t < 4; t++) acc[s][t] = (f32x4){0.f, 0.f, 0.f, 0.f};

  float4 xa[8];
  int4 wbh[2], wbl[2];

  auto issue = [&](int kc) {
#pragma unroll
    for (int i = 0; i < 8; i++) {
      int r = (tid >> 4) + i * 16;
      int kk = (tid & 15) << 2;
      xa[i] = *reinterpret_cast<const float4*>(
          x + (size_t)(rowBase + r) * D_DIM + kc + kk);
    }
#pragma unroll
    for (int i = 0; i < 2; i++) {
      int idx = tid + i * 256;
      int n = idx >> 3;
      int kk = (idx & 7) << 3;
      wbh[i] = *reinterpret_cast<const int4*>(w1t_hi + n * D_DIM + kc + kk);
      wbl[i] = *reinterpret_cast<const int4*>(w1t_lo + n * D_DIM + kc + kk);
    }
  };
  auto cvt_store = [&]() {
#pragma unroll
    for (int i = 0; i < 8; i++) {
      const float4 v = xa[i];
      unsigned short h0 = bf16_rn(v.x), h1 = bf16_rn(v.y), h2 = bf16_rn(v.z), h3 = bf16_rn(v.w);
      unsigned short l0 = bf16_rn(v.x - bf16_f(h0));
      unsigned short l1 = bf16_rn(v.y - bf16_f(h1));
      unsigned short l2 = bf16_rn(v.z - bf16_f(h2));
      unsigned short l3 = bf16_rn(v.w - bf16_f(h3));
      int a = ((tid >> 4) + i * 16) * LDK + ((tid & 15) << 2);
      *reinterpret_cast<u16x4*>(&A_hi[a]) = (u16x4){h0, h1, h2, h3};
      *reinterpret_cast<u16x4*>(&A_lo[a]) = (u16x4){l0, l1, l2, l3};
    }
#pragma unroll
    for (int i = 0; i < 2; i++) {
      int idx = tid + i * 256;
      int n = idx >> 3;
      int kk = (idx & 7) << 3;
      *reinterpret_cast<int4*>(&Bh[n * LDK + kk]) = wbh[i];
      *reinterpret_cast<int4*>(&Bl[n * LDK + kk]) = wbl[i];
    }
  };
  auto mfma_phase = [&]() {
#pragma unroll
    for (int k2 = 0; k2 < 2; k2++) {
      int ko = k2 * 32 + (lane >> 4) * 8;
      bf16x8 afh[2], afl[2], bfh[4], bfl[4];
#pragma unroll
      for (int s = 0; s < 2; s++) {
        int r = wave * 32 + s * 16 + (lane & 15);
        afh[s] = *reinterpret_cast<const bf16x8*>(&A_hi[r * LDK + ko]);
        afl[s] = *reinterpret_cast<const bf16x8*>(&A_lo[r * LDK + ko]);
      }
#pragma unroll
      for (int t = 0; t < 4; t++) {
        int n = t * 16 + (lane & 15);
        bfh[t] = *reinterpret_cast<const bf16x8*>(&Bh[n * LDK + ko]);
        bfl[t] = *reinterpret_cast<const bf16x8*>(&Bl[n * LDK + ko]);
      }
#pragma unroll
      for (int s = 0; s < 2; s++)
#pragma unroll
        for (int t = 0; t < 4; t++) {
          acc[s][t] = __builtin_amdgcn_mfma_f32_16x16x32_bf16(afl[s], bfh[t], acc[s][t], 0, 0, 0);
          acc[s][t] = __builtin_amdgcn_mfma_f32_16x16x32_bf16(afh[s], bfl[t], acc[s][t], 0, 0, 0);
          acc[s][t] = __builtin_amdgcn_mfma_f32_16x16x32_bf16(afh[s], bfh[t], acc[s][t], 0, 0, 0);
        }
    }
  };

  issue(0);
  cvt_store();
  __syncthreads();
  for (int kc8 = 0; kc8 < 8; kc8++) {
    if (kc8 < 7) issue((kc8 + 1) * BK);   // loads in flight during MFMA phase
    mfma_phase();
    __syncthreads();
    if (kc8 < 7) {
      cvt_store();
      __syncthreads();
    }
  }

  // epilogue: h = gelu(acc + ab1); score = h @ aW2 + ab2; w = sigmoid(score)
  int c0 = lane & 15, quad = lane >> 4;
  float w2v[4], b1v[4];
#pragma unroll
  for (int t = 0; t < 4; t++) {
    w2v[t] = aW2[t * 16 + c0];
    b1v[t] = ab1[t * 16 + c0];
  }
  float bias2 = ab2[0];
#pragma unroll
  for (int s = 0; s < 2; s++) {
    float p[4] = {0.f, 0.f, 0.f, 0.f};
#pragma unroll
    for (int t = 0; t < 4; t++)
#pragma unroll
      for (int r = 0; r < 4; r++) {
        float h = gelu_f(acc[s][t][r] + b1v[t]);
        p[r] += h * w2v[t];
      }
#pragma unroll
    for (int off = 1; off < 16; off <<= 1)
#pragma unroll
      for (int r = 0; r < 4; r++) p[r] += __shfl_xor(p[r], off, 64);
    if (c0 == 0) {
      int row = rowBase + wave * 32 + s * 16 + quad * 4;
#pragma unroll
      for (int r = 0; r < 4; r++) {
        float sc = p[r] + bias2;
        wout[row + r] = 1.0f / (1.0f + expf(-sc));
      }
    }
  }

  // ---- fused top-k: last block to finish computes T/Icut for all bags ----
  __threadfence();
  __syncthreads();
  if (tid == 0) rank_s = atomicAdd(&counters[0], 1u);
  __syncthreads();
  if (rank_s != (unsigned int)(gridDim.x - 1)) return;
  __threadfence();  // make all blocks' wout stores visible

  // each wave: bags {wave, wave+4}; independent shuffle-only binary search
  for (int bb = wave; bb < B_BAGS; bb += 4) {
    const float* w = wout + bb * N_INST;
    unsigned int v[128];
#pragma unroll
    for (int j = 0; j < 128; j++) v[j] = __float_as_uint(w[j * 64 + lane]);

    auto wsum = [&](int c) -> int {
#pragma unroll
      for (int off = 1; off < 64; off <<= 1) c += __shfl_xor(c, off, 64);
      return c;
    };

    unsigned int lo = 0u, hi = 0x3F800001u;
    while (hi - lo > 1u) {
      unsigned int mid = lo + ((hi - lo) >> 1);
      int c = 0;
#pragma unroll
      for (int j = 0; j < 128; j++) c += (v[j] >= mid) ? 1 : 0;
      if (wsum(c) >= TOPK_K) lo = mid; else hi = mid;
    }
    unsigned int T = lo;

    int c1 = 0;
#pragma unroll
    for (int j = 0; j < 128; j++) c1 += (v[j] > T) ? 1 : 0;
    c1 = wsum(c1);
    int needed = TOPK_K - c1;   // >= 1

    unsigned long long tm0 = 0ull, tm1 = 0ull;
#pragma unroll
    for (int j = 0; j < 64; j++) tm0 |= (v[j] == T ? 1ull : 0ull) << j;
#pragma unroll
    for (int j = 0; j < 64; j++) tm1 |= (v[64 + j] == T ? 1ull : 0ull) << j;

    // smallest m with count(v==T && idx<=m) >= needed, idx = j*64+lane
    int lom = -1, him = N_INST - 1;
    while (him - lom > 1) {
      int mid = (lom + him) >> 1;
      int c = 0;
      if (mid >= lane) {
        unsigned int jmax = (unsigned int)(mid - lane) >> 6;   // 0..127
        unsigned int j0 = jmax > 63u ? 63u : jmax;
        unsigned long long m0 = (2ull << j0) - 1ull;
        unsigned long long m1 = 0ull;
        if (jmax >= 64u) {
          unsigned int j1 = (jmax - 64u) > 63u ? 63u : (jmax - 64u);
          m1 = (2ull << j1) - 1ull;
        }
        c = __popcll(tm0 & m0) + __popcll(tm1 & m1);
      }
      if (wsum(c) >= needed) him = mid; else lom = mid;
    }
    if (lane == 0) {
      meta[bb] = T;
      ((int*)meta)[8 + bb] = him;
    }
  }
}

// ---------------- kernel 3: weighted gather partial sums (float4, 2 rows/iter) ----
__global__ __launch_bounds__(256) void k_gather(const float* __restrict__ x,
                                                const float* __restrict__ wout,
                                                const unsigned int* __restrict__ meta,
                                                float* __restrict__ part3) {
  int b = blockIdx.x >> 6;
  int blk = blockIdx.x & 63;
  unsigned int T = meta[b];
  int Icut = ((const int*)meta)[8 + b];
  int tid = threadIdx.x;

  __shared__ int idxs[128];
  __shared__ float wgts[128];
  __shared__ int wcnt[2];
  __shared__ float4 xfer[128];

  int r = blk * 128 + tid;
  bool sel = false;
  float wvv = 0.f;
  int pos = 0;
  if (tid < 128) {
    wvv = wout[b * N_INST + r];
    unsigned int wu = __float_as_uint(wvv);
    sel = (wu > T) || (wu == T && r <= Icut);
    unsigned long long m = __ballot(sel);
    int lane = tid & 63;
    pos = __popcll(m & ((1ull << lane) - 1ull));
    if (lane == 0) wcnt[tid >> 6] = __popcll(m);
  }
  __syncthreads();
  int total = wcnt[0] + wcnt[1];
  if (sel) {
    int base = (tid >= 64) ? wcnt[0] : 0;
    idxs[base + pos] = r;
    wgts[base + pos] = wvv;
  }
  __syncthreads();

  int half = tid >> 7;      // 0/1: which of the two rows this iteration
  int L = tid & 127;        // 128 lanes x float4 = 512 cols
  float4 acc = {0.f, 0.f, 0.f, 0.f};
  const float* xb = x + (size_t)b * N_INST * D_DIM;
  int i2 = total & ~1;
#pragma unroll 4
  for (int i = 0; i < i2; i += 2) {
    int rr = idxs[i + half];
    float ww = wgts[i + half];
    const float4 xv = *reinterpret_cast<const float4*>(xb + (size_t)rr * D_DIM + L * 4);
    acc.x += ww * xv.x; acc.y += ww * xv.y; acc.z += ww * xv.z; acc.w += ww * xv.w;
  }
  if ((total & 1) && half == 0) {
    int rr = idxs[i2];
    float ww = wgts[i2];
    const float4 xv = *reinterpret_cast<const float4*>(xb + (size_t)rr * D_DIM + L * 4);
    acc.x += ww * xv.x; acc.y += ww * xv.y; acc.z += ww * xv.z; acc.w += ww * xv.w;
  }
  if (half == 1) xfer[L] = acc;
  __syncthreads();
  if (half == 0) {
    float4 o = xfer[L];
    acc.x += o.x; acc.y += o.y; acc.z += o.z; acc.w += o.w;
    *reinterpret_cast<float4*>(part3 + (size_t)(b * 64 + blk) * D_DIM + L * 4) = acc;
  }
}

// ---------------- projection MLP: split-K, 64 blocks per layer ----------------
__global__ __launch_bounds__(256) void k_proj1(const float* __restrict__ part3,
                                               const float* __restrict__ pW1,
                                               float* __restrict__ part1) {
  int jt = blockIdx.x & 7, kt = blockIdx.x >> 3;
  __shared__ float emb_s[512];   // [b*64 + d0], d = kt*64 + d0
  int tid = threadIdx.x;
#pragma unroll
  for (int h = 0; h < 2; h++) {
    int vi = tid + h * 256;
    int b = vi >> 6, d0 = vi & 63;
    const float* p = part3 + (size_t)b * 64 * 512 + kt * 64 + d0;
    float e = 0.f;
#pragma unroll 8
    for (int j = 0; j < 64; j++) e += p[j * 512];
    emb_s[vi] = e * (1.0f / TOPK_K);
  }
  __syncthreads();
  int col = tid & 63, bg = tid >> 6;   // bags bg*2, bg*2+1
  float a0 = 0.f, a1 = 0.f;
  const float* wrow = pW1 + (size_t)(kt * 64) * 512 + jt * 64 + col;
#pragma unroll 8
  for (int q = 0; q < 64; q++) {
    float wq = wrow[q * 512];
    a0 += emb_s[(bg * 2) * 64 + q] * wq;
    a1 += emb_s[(bg * 2 + 1) * 64 + q] * wq;
  }
  part1[kt * 4096 + (bg * 2) * 512 + jt * 64 + col] = a0;
  part1[kt * 4096 + (bg * 2 + 1) * 512 + jt * 64 + col] = a1;
}

__global__ __launch_bounds__(256) void k_proj2(const float* __restrict__ part1,
                                               const float* __restrict__ pb1,
                                               const float* __restrict__ pW2,
                                               float* __restrict__ part2,
                                               const float* __restrict__ pb2,
                                               float* __restrict__ out,
                                               unsigned int* __restrict__ counters) {
  int jt = blockIdx.x & 7, kt = blockIdx.x >> 3;
  __shared__ float h_s[512];   // [b*64 + j0], j = kt*64 + j0
  __shared__ unsigned int rank_s;
  int tid = threadIdx.x;
#pragma unroll
  for (int h = 0; h < 2; h++) {
    int vi = tid + h * 256;
    int b = vi >> 6, j0 = vi & 63;
    int jj = kt * 64 + j0;
    float s = pb1[jj];
#pragma unroll
    for (int p = 0; p < 8; p++) s += part1[p * 4096 + b * 512 + jj];
    h_s[vi] = gelu_f(s);
  }
  __syncthreads();
  int col = tid & 63, bg = tid >> 6;
  float a0 = 0.f, a1 = 0.f;
  const float* wrow = pW2 + (size_t)(kt * 64) * 512 + jt * 64 + col;
#pragma unroll 8
  for (int q = 0; q < 64; q++) {
    float wq = wrow[q * 512];
    a0 += h_s[(bg * 2) * 64 + q] * wq;
    a1 += h_s[(bg * 2 + 1) * 64 + q] * wq;
  }
  part2[kt * 4096 + (bg * 2) * 512 + jt * 64 + col] = a0;
  part2[kt * 4096 + (bg * 2 + 1) * 512 + jt * 64 + col] = a1;

  // ---- fused final reduce: last of the 64 blocks writes out[8][512] ----
  __threadfence();
  __syncthreads();
  if (tid == 0) rank_s = atomicAdd(&counters[1], 1u);
  __syncthreads();
  if (rank_s != (unsigned int)(gridDim.x - 1)) return;
  __threadfence();
  for (int oo = tid; oo < 4096; oo += 256) {
    float s = pb2[oo & 511];
#pragma unroll
    for (int p = 0; p < 8; p++) s += part2[p * 4096 + oo];
    out[oo] = s;
  }
}

extern "C" void kernel_launch(void* const* d_in, const int* in_sizes, int n_in,
                              void* d_out, int out_size, void* d_ws, size_t ws_size,
                              hipStream_t stream) {
  (void)in_sizes; (void)n_in; (void)out_size; (void)ws_size;
  const float* x   = (const float*)d_in[0];
  const float* aW1 = (const float*)d_in[1];
  const float* ab1 = (const float*)d_in[2];
  const float* aW2 = (const float*)d_in[3];
  const float* ab2 = (const float*)d_in[4];
  const float* pW1 = (const float*)d_in[5];
  const float* pb1 = (const float*)d_in[6];
  const float* pW2 = (const float*)d_in[7];
  const float* pb2 = (const float*)d_in[8];

  float* out  = (float*)d_out;
  float* wout = out + B_BAGS * D_DIM;  // weights output region [8][8192]

  char* ws = (char*)d_ws;
  unsigned short* w1t_hi = (unsigned short*)(ws + WS_W1T_HI);
  unsigned short* w1t_lo = (unsigned short*)(ws + WS_W1T_LO);
  unsigned int*   meta   = (unsigned int*)(ws + WS_META);
  unsigned int*   counters = meta + 16;
  float* part3 = (float*)(ws + WS_PART3);
  float* part1 = (float*)(ws + WS_PART1);
  float* part2 = (float*)(ws + WS_PART2);

  k_prep<<<dim3((H_ATT * D_DIM + 255) / 256), dim3(256), 0, stream>>>(aW1, w1t_hi, w1t_lo, counters);
  k_scores<<<dim3(ROWS_TOTAL / BM), dim3(256), 0, stream>>>(x, w1t_hi, w1t_lo, ab1, aW2, ab2, wout, meta, counters);
  k_gather<<<dim3(B_BAGS * 64), dim3(256), 0, stream>>>(x, wout, meta, part3);
  k_proj1<<<dim3(64), dim3(256), 0, stream>>>(part3, pW1, part1);
  k_proj2<<<dim3(64), dim3(256), 0, stream>>>(part1, pb1, pW2, part2, pb2, out, counters);
}

// Round 5
// 293.161 us; speedup vs baseline: 1.2929x; 1.2929x over previous
//
#include <hip/hip_runtime.h>
#include <math.h>

#define B_BAGS 8
#define N_INST 8192
#define D_DIM  512
#define H_ATT  64
#define TOPK_K 2457
#define ROWS_TOTAL (B_BAGS * N_INST)

typedef __attribute__((ext_vector_type(8))) short bf16x8;
typedef __attribute__((ext_vector_type(4))) float f32x4;

// ---- workspace layout (bytes) ----
#define WS_W1T_HI 0                          // [64][512] bf16 bits
#define WS_W1T_LO 65536                      // [64][512] bf16 bits
#define WS_META   131072                     // 8 uint T, 8 int Icut
#define WS_PART3  131584                     // [8][64][512] f32 gather partials (1 MB)
#define WS_PART1  (WS_PART3 + 8*64*512*4)    // [8kt][8b][512] f32 layer1 partials
#define WS_PART2  (WS_PART1 + 8*8*512*4)     // [8kt][8b][512] f32 layer2 partials

__device__ __forceinline__ unsigned short bf16_rn(float f) {
  unsigned int x = __float_as_uint(f);
  unsigned int r = (x + 0x7FFFu + ((x >> 16) & 1u)) >> 16;
  return (unsigned short)r;
}
__device__ __forceinline__ float bf16_f(unsigned short u) {
  return __uint_as_float(((unsigned int)u) << 16);
}
__device__ __forceinline__ float gelu_f(float v) {
  float u = 0.7978845608028654f * (v + 0.044715f * v * v * v);
  return 0.5f * v * (1.0f + tanhf(u));
}

// truncation-based hi/lo split of 8 consecutive fp32 -> bf16x8 hi + lo.
__device__ __forceinline__ void cvt_hilo(const float4 u, const float4 v,
                                         bf16x8& h, bf16x8& l) {
  float f[8] = {u.x, u.y, u.z, u.w, v.x, v.y, v.z, v.w};
#pragma unroll
  for (int i = 0; i < 8; i++) {
    unsigned int b = __float_as_uint(f[i]);
    unsigned int hb = b & 0xFFFF0000u;
    float r = f[i] - __uint_as_float(hb);
    h[i] = (short)(b >> 16);
    l[i] = (short)(__float_as_uint(r) >> 16);
  }
}

// ---------------- kernel 0: transpose + hi/lo split of aW1 ----------------
__global__ __launch_bounds__(256) void k_prep(const float* __restrict__ aW1,
                                              unsigned short* __restrict__ hi,
                                              unsigned short* __restrict__ lo) {
  int o = blockIdx.x * 256 + threadIdx.x;   // over 64*512 outputs, layout [n][k]
  if (o >= H_ATT * D_DIM) return;
  int n = o >> 9;
  int k = o & 511;
  float v = aW1[k * H_ATT + n];
  unsigned short h = bf16_rn(v);
  unsigned short l = bf16_rn(v - bf16_f(h));
  hi[o] = h;
  lo[o] = l;
}

// ---------------- kernel 1: score MLP -> sigmoid weights ----------------
// No LDS, no barriers. 1024 blocks x 64 rows (4 blocks/CU, ~16 waves/CU).
// Each wave owns 16 rows; lanes l, l+16, l+32, l+48 together cover one 128B
// line of a row. A and B both register-double-buffered one k-step ahead.
#define BM 64

__global__ __launch_bounds__(256) void k_scores(
    const float* __restrict__ x,
    const unsigned short* __restrict__ w1t_hi,
    const unsigned short* __restrict__ w1t_lo,
    const float* __restrict__ ab1, const float* __restrict__ aW2,
    const float* __restrict__ ab2, float* __restrict__ wout) {
  int tid = threadIdx.x;
  int wave = tid >> 6, lane = tid & 63;
  int c0 = lane & 15, quad = lane >> 4;
  int rowBase = blockIdx.x * BM + wave * 16;
  const int kq = quad * 8;   // lane's k offset within a 32-wide k-step

  const float* xr = x + (size_t)(rowBase + c0) * D_DIM;
  const unsigned short* bh0 = w1t_hi + c0 * D_DIM + kq;  // + t*16*D_DIM + ks*32
  const unsigned short* bl0 = w1t_lo + c0 * D_DIM + kq;

  f32x4 acc[4];
#pragma unroll
  for (int t = 0; t < 4; t++) acc[t] = (f32x4){0.f, 0.f, 0.f, 0.f};

  // double buffers
  float4 a0, a1, na0, na1;
  bf16x8 bfh[4], bfl[4], nbh[4], nbl[4];

  a0 = *reinterpret_cast<const float4*>(xr + kq);
  a1 = *reinterpret_cast<const float4*>(xr + kq + 4);
#pragma unroll
  for (int t = 0; t < 4; t++) {
    bfh[t] = *reinterpret_cast<const bf16x8*>(bh0 + t * 16 * D_DIM);
    bfl[t] = *reinterpret_cast<const bf16x8*>(bl0 + t * 16 * D_DIM);
  }

  for (int ks = 0; ks < 16; ks++) {
    if (ks < 15) {
      int kb = (ks + 1) * 32;
      na0 = *reinterpret_cast<const float4*>(xr + kb + kq);
      na1 = *reinterpret_cast<const float4*>(xr + kb + kq + 4);
#pragma unroll
      for (int t = 0; t < 4; t++) {
        nbh[t] = *reinterpret_cast<const bf16x8*>(bh0 + t * 16 * D_DIM + kb);
        nbl[t] = *reinterpret_cast<const bf16x8*>(bl0 + t * 16 * D_DIM + kb);
      }
    }
    bf16x8 afh, afl;
    cvt_hilo(a0, a1, afh, afl);
#pragma unroll
    for (int t = 0; t < 4; t++) {
      acc[t] = __builtin_amdgcn_mfma_f32_16x16x32_bf16(afl, bfh[t], acc[t], 0, 0, 0);
      acc[t] = __builtin_amdgcn_mfma_f32_16x16x32_bf16(afh, bfl[t], acc[t], 0, 0, 0);
      acc[t] = __builtin_amdgcn_mfma_f32_16x16x32_bf16(afh, bfh[t], acc[t], 0, 0, 0);
    }
    a0 = na0; a1 = na1;
#pragma unroll
    for (int t = 0; t < 4; t++) { bfh[t] = nbh[t]; bfl[t] = nbl[t]; }
  }

  // epilogue: h = gelu(acc + ab1); score = h @ aW2 + ab2; w = sigmoid(score)
  float w2v[4], b1v[4];
#pragma unroll
  for (int t = 0; t < 4; t++) {
    w2v[t] = aW2[t * 16 + c0];
    b1v[t] = ab1[t * 16 + c0];
  }
  float bias2 = ab2[0];
  float p[4] = {0.f, 0.f, 0.f, 0.f};
#pragma unroll
  for (int t = 0; t < 4; t++)
#pragma unroll
    for (int r = 0; r < 4; r++) {
      float h = gelu_f(acc[t][r] + b1v[t]);
      p[r] += h * w2v[t];
    }
#pragma unroll
  for (int off = 1; off < 16; off <<= 1)
#pragma unroll
    for (int r = 0; r < 4; r++) p[r] += __shfl_xor(p[r], off, 64);
  if (c0 == 0) {
    int row = rowBase + quad * 4;
#pragma unroll
    for (int r = 0; r < 4; r++) {
      float sc = p[r] + bias2;
      wout[row + r] = 1.0f / (1.0f + expf(-sc));
    }
  }
}

// ---------------- kernel 2: exact top-k threshold per bag ----------------
__global__ __launch_bounds__(256) void k_topk(const float* __restrict__ wout,
                                              unsigned int* __restrict__ meta) {
  int b = blockIdx.x;
  const float* w = wout + b * N_INST;
  int tid = threadIdx.x;
  unsigned int v[32];
#pragma unroll
  for (int j = 0; j < 32; j++) v[j] = __float_as_uint(w[j * 256 + tid]);

  __shared__ int red[2][4];
  int lane = tid & 63, wv = tid >> 6;
  int pb = 0;

  auto blocksum = [&](int c) -> int {
#pragma unroll
    for (int off = 32; off > 0; off >>= 1) c += __shfl_down(c, off, 64);
    if (lane == 0) red[pb][wv] = c;
    __syncthreads();
    int s = red[pb][0] + red[pb][1] + red[pb][2] + red[pb][3];
    pb ^= 1;
    return s;
  };

  // phase 1: largest T with count(bits >= T) >= K (weights in (0,1) -> bits monotone)
  unsigned int lo = 0u, hi = 0x3F800001u;
  while (hi - lo > 1u) {
    unsigned int mid = lo + ((hi - lo) >> 1);
    int c = 0;
#pragma unroll
    for (int j = 0; j < 32; j++) c += (v[j] >= mid) ? 1 : 0;
    int s = blocksum(c);
    if (s >= TOPK_K) lo = mid; else hi = mid;
  }
  unsigned int T = lo;

  // phase 2: count strictly greater
  int c1;
  {
    int c = 0;
#pragma unroll
    for (int j = 0; j < 32; j++) c += (v[j] > T) ? 1 : 0;
    c1 = blocksum(c);
  }
  int needed = TOPK_K - c1;  // >= 1

  // phase 3: smallest m with count(v==T && idx<=m) >= needed, idx = j*256+tid.
  unsigned int tm = 0;
#pragma unroll
  for (int j = 0; j < 32; j++) tm |= (v[j] == T ? 1u : 0u) << j;
  int lom = -1, him = N_INST - 1;
  while (him - lom > 1) {
    int mid = (lom + him) >> 1;
    unsigned int mask = 0u;
    if (mid >= tid) {
      unsigned int jmax = (unsigned int)(mid - tid) >> 8;   // 0..31
      mask = (2u << jmax) - 1u;
    }
    int s = blocksum((int)__popc(tm & mask));
    if (s >= needed) him = mid; else lom = mid;
  }
  if (tid == 0) {
    meta[b] = T;
    ((int*)meta)[8 + b] = him;
  }
}

// ---------------- kernel 3: weighted gather partial sums (float4, 2 rows/iter) ----
__global__ __launch_bounds__(256) void k_gather(const float* __restrict__ x,
                                                const float* __restrict__ wout,
                                                const unsigned int* __restrict__ meta,
                                                float* __restrict__ part3) {
  int b = blockIdx.x >> 6;
  int blk = blockIdx.x & 63;
  unsigned int T = meta[b];
  int Icut = ((const int*)meta)[8 + b];
  int tid = threadIdx.x;

  __shared__ int idxs[128];
  __shared__ float wgts[128];
  __shared__ int wcnt[2];
  __shared__ float4 xfer[128];

  int r = blk * 128 + tid;
  bool sel = false;
  float wvv = 0.f;
  int pos = 0;
  if (tid < 128) {
    wvv = wout[b * N_INST + r];
    unsigned int wu = __float_as_uint(wvv);
    sel = (wu > T) || (wu == T && r <= Icut);
    unsigned long long m = __ballot(sel);
    int lane = tid & 63;
    pos = __popcll(m & ((1ull << lane) - 1ull));
    if (lane == 0) wcnt[tid >> 6] = __popcll(m);
  }
  __syncthreads();
  int total = wcnt[0] + wcnt[1];
  if (sel) {
    int base = (tid >= 64) ? wcnt[0] : 0;
    idxs[base + pos] = r;
    wgts[base + pos] = wvv;
  }
  __syncthreads();

  int half = tid >> 7;      // 0/1: which of the two rows this iteration
  int L = tid & 127;        // 128 lanes x float4 = 512 cols
  float4 acc = {0.f, 0.f, 0.f, 0.f};
  const float* xb = x + (size_t)b * N_INST * D_DIM;
  int i2 = total & ~1;
#pragma unroll 4
  for (int i = 0; i < i2; i += 2) {
    int rr = idxs[i + half];
    float ww = wgts[i + half];
    const float4 xv = *reinterpret_cast<const float4*>(xb + (size_t)rr * D_DIM + L * 4);
    acc.x += ww * xv.x; acc.y += ww * xv.y; acc.z += ww * xv.z; acc.w += ww * xv.w;
  }
  if ((total & 1) && half == 0) {
    int rr = idxs[i2];
    float ww = wgts[i2];
    const float4 xv = *reinterpret_cast<const float4*>(xb + (size_t)rr * D_DIM + L * 4);
    acc.x += ww * xv.x; acc.y += ww * xv.y; acc.z += ww * xv.z; acc.w += ww * xv.w;
  }
  if (half == 1) xfer[L] = acc;
  __syncthreads();
  if (half == 0) {
    float4 o = xfer[L];
    acc.x += o.x; acc.y += o.y; acc.z += o.z; acc.w += o.w;
    *reinterpret_cast<float4*>(part3 + (size_t)(b * 64 + blk) * D_DIM + L * 4) = acc;
  }
}

// ---------------- projection MLP: split-K, 64 blocks per layer ----------------
__global__ __launch_bounds__(256) void k_proj1(const float* __restrict__ part3,
                                               const float* __restrict__ pW1,
                                               float* __restrict__ part1) {
  int jt = blockIdx.x & 7, kt = blockIdx.x >> 3;
  __shared__ float emb_s[512];   // [b*64 + d0], d = kt*64 + d0
  int tid = threadIdx.x;
#pragma unroll
  for (int h = 0; h < 2; h++) {
    int vi = tid + h * 256;
    int b = vi >> 6, d0 = vi & 63;
    const float* p = part3 + (size_t)b * 64 * 512 + kt * 64 + d0;
    float e = 0.f;
#pragma unroll 8
    for (int j = 0; j < 64; j++) e += p[j * 512];
    emb_s[vi] = e * (1.0f / TOPK_K);
  }
  __syncthreads();
  int col = tid & 63, bg = tid >> 6;   // bags bg*2, bg*2+1
  float a0 = 0.f, a1 = 0.f;
  const float* wrow = pW1 + (size_t)(kt * 64) * 512 + jt * 64 + col;
#pragma unroll 8
  for (int q = 0; q < 64; q++) {
    float wq = wrow[q * 512];
    a0 += emb_s[(bg * 2) * 64 + q] * wq;
    a1 += emb_s[(bg * 2 + 1) * 64 + q] * wq;
  }
  part1[kt * 4096 + (bg * 2) * 512 + jt * 64 + col] = a0;
  part1[kt * 4096 + (bg * 2 + 1) * 512 + jt * 64 + col] = a1;
}

__global__ __launch_bounds__(256) void k_proj2(const float* __restrict__ part1,
                                               const float* __restrict__ pb1,
                                               const float* __restrict__ pW2,
                                               float* __restrict__ part2) {
  int jt = blockIdx.x & 7, kt = blockIdx.x >> 3;
  __shared__ float h_s[512];   // [b*64 + j0], j = kt*64 + j0
  int tid = threadIdx.x;
#pragma unroll
  for (int h = 0; h < 2; h++) {
    int vi = tid + h * 256;
    int b = vi >> 6, j0 = vi & 63;
    int jj = kt * 64 + j0;
    float s = pb1[jj];
#pragma unroll
    for (int p = 0; p < 8; p++) s += part1[p * 4096 + b * 512 + jj];
    h_s[vi] = gelu_f(s);
  }
  __syncthreads();
  int col = tid & 63, bg = tid >> 6;
  float a0 = 0.f, a1 = 0.f;
  const float* wrow = pW2 + (size_t)(kt * 64) * 512 + jt * 64 + col;
#pragma unroll 8
  for (int q = 0; q < 64; q++) {
    float wq = wrow[q * 512];
    a0 += h_s[(bg * 2) * 64 + q] * wq;
    a1 += h_s[(bg * 2 + 1) * 64 + q] * wq;
  }
  part2[kt * 4096 + (bg * 2) * 512 + jt * 64 + col] = a0;
  part2[kt * 4096 + (bg * 2 + 1) * 512 + jt * 64 + col] = a1;
}

__global__ __launch_bounds__(512) void k_proj3(const float* __restrict__ part2,
                                               const float* __restrict__ pb2,
                                               float* __restrict__ out) {
  int o = blockIdx.x * 512 + threadIdx.x;   // o = b*512 + j
  int bj = o & 511;
  float s = pb2[bj];
#pragma unroll
  for (int p = 0; p < 8; p++) s += part2[p * 4096 + o];
  out[o] = s;
}

extern "C" void kernel_launch(void* const* d_in, const int* in_sizes, int n_in,
                              void* d_out, int out_size, void* d_ws, size_t ws_size,
                              hipStream_t stream) {
  (void)in_sizes; (void)n_in; (void)out_size; (void)ws_size;
  const float* x   = (const float*)d_in[0];
  const float* aW1 = (const float*)d_in[1];
  const float* ab1 = (const float*)d_in[2];
  const float* aW2 = (const float*)d_in[3];
  const float* ab2 = (const float*)d_in[4];
  const float* pW1 = (const float*)d_in[5];
  const float* pb1 = (const float*)d_in[6];
  const float* pW2 = (const float*)d_in[7];
  const float* pb2 = (const float*)d_in[8];

  float* out  = (float*)d_out;
  float* wout = out + B_BAGS * D_DIM;  // weights output region [8][8192]

  char* ws = (char*)d_ws;
  unsigned short* w1t_hi = (unsigned short*)(ws + WS_W1T_HI);
  unsigned short* w1t_lo = (unsigned short*)(ws + WS_W1T_LO);
  unsigned int*   meta   = (unsigned int*)(ws + WS_META);
  float* part3 = (float*)(ws + WS_PART3);
  float* part1 = (float*)(ws + WS_PART1);
  float* part2 = (float*)(ws + WS_PART2);

  k_prep<<<dim3((H_ATT * D_DIM + 255) / 256), dim3(256), 0, stream>>>(aW1, w1t_hi, w1t_lo);
  k_scores<<<dim3(ROWS_TOTAL / BM), dim3(256), 0, stream>>>(x, w1t_hi, w1t_lo, ab1, aW2, ab2, wout);
  k_topk<<<dim3(B_BAGS), dim3(256), 0, stream>>>(wout, meta);
  k_gather<<<dim3(B_BAGS * 64), dim3(256), 0, stream>>>(x, wout, meta, part3);
  k_proj1<<<dim3(64), dim3(256), 0, stream>>>(part3, pW1, part1);
  k_proj2<<<dim3(64), dim3(256), 0, stream>>>(part1, pb1, pW2, part2);
  k_proj3<<<dim3(B_BAGS), dim3(512), 0, stream>>>(part2, pb2, out);
}

// Round 6
// 271.762 us; speedup vs baseline: 1.3947x; 1.0787x over previous
//
#include <hip/hip_runtime.h>
#include <math.h>

#define B_BAGS 8
#define N_INST 8192
#define D_DIM  512
#define H_ATT  64
#define TOPK_K 2457
#define ROWS_TOTAL (B_BAGS * N_INST)

typedef __attribute__((ext_vector_type(8))) short bf16x8;
typedef __attribute__((ext_vector_type(4))) float f32x4;

// ---- workspace layout (bytes) ----
#define WS_W1P_HI 0                          // packed MFMA B-frags, 32768 ushort
#define WS_W1P_LO 65536                      // packed MFMA B-frags, 32768 ushort
#define WS_META   131072                     // 8 uint T, 8 int Icut
#define WS_PART3  131584                     // [8][64][512] f32 gather partials (1 MB)
#define WS_PART1  (WS_PART3 + 8*64*512*4)    // [8kt][8b][512] f32 layer1 partials
#define WS_PART2  (WS_PART1 + 8*8*512*4)     // [8kt][8b][512] f32 layer2 partials

__device__ __forceinline__ unsigned short bf16_rn(float f) {
  unsigned int x = __float_as_uint(f);
  unsigned int r = (x + 0x7FFFu + ((x >> 16) & 1u)) >> 16;
  return (unsigned short)r;
}
__device__ __forceinline__ float bf16_f(unsigned short u) {
  return __uint_as_float(((unsigned int)u) << 16);
}
__device__ __forceinline__ float gelu_f(float v) {
  float u = 0.7978845608028654f * (v + 0.044715f * v * v * v);
  return 0.5f * v * (1.0f + tanhf(u));
}

// truncation-based hi/lo split of 8 consecutive fp32 -> bf16x8 hi + lo.
__device__ __forceinline__ void cvt_hilo(const float4 u, const float4 v,
                                         bf16x8& h, bf16x8& l) {
  float f[8] = {u.x, u.y, u.z, u.w, v.x, v.y, v.z, v.w};
#pragma unroll
  for (int i = 0; i < 8; i++) {
    unsigned int b = __float_as_uint(f[i]);
    unsigned int hb = b & 0xFFFF0000u;
    float r = f[i] - __uint_as_float(hb);
    h[i] = (short)(b >> 16);
    l[i] = (short)(__float_as_uint(r) >> 16);
  }
}

// ---------------- kernel 0: pack aW1 into MFMA-fragment-sequential layout ----
// For (ks in [0,16), t in [0,4), lane in [0,64)): lane's B-frag is
// B[k][n] with n = t*16 + (lane&15), k = ks*32 + (lane>>4)*8 + j, j in [0,8).
// Packed at offset ((ks*4 + t)*64 + lane)*8 + j  ->  hot-loop loads are
// base + lane*16B: fully coalesced (1 txn/instr instead of 64).
__global__ __launch_bounds__(256) void k_prep(const float* __restrict__ aW1,
                                              unsigned short* __restrict__ hi,
                                              unsigned short* __restrict__ lo) {
  int tau = blockIdx.x * 256 + threadIdx.x;   // (ks,t,lane) tuple, 4096 total
  if (tau >= 4096) return;
  int ks = tau >> 8, t = (tau >> 6) & 3, lane = tau & 63;
  int n = t * 16 + (lane & 15);
  int kb = ks * 32 + (lane >> 4) * 8;
#pragma unroll
  for (int j = 0; j < 8; j++) {
    float v = aW1[(kb + j) * H_ATT + n];
    unsigned short h = bf16_rn(v);
    unsigned short l = bf16_rn(v - bf16_f(h));
    hi[tau * 8 + j] = h;
    lo[tau * 8 + j] = l;
  }
}

// ---------------- kernel 1: score MLP -> sigmoid weights ----------------
// No LDS, no barriers. 1024 blocks x 64 rows (4 blocks/CU, ~16 waves/CU).
// Each wave owns 16 rows. B-frags from the packed layout (coalesced);
// A and B register-double-buffered one k-step ahead.
#define BM 64

__global__ __launch_bounds__(256) void k_scores(
    const float* __restrict__ x,
    const unsigned short* __restrict__ w1p_hi,
    const unsigned short* __restrict__ w1p_lo,
    const float* __restrict__ ab1, const float* __restrict__ aW2,
    const float* __restrict__ ab2, float* __restrict__ wout) {
  int tid = threadIdx.x;
  int wave = tid >> 6, lane = tid & 63;
  int c0 = lane & 15, quad = lane >> 4;
  int rowBase = blockIdx.x * BM + wave * 16;
  const int kq = quad * 8;   // lane's k offset within a 32-wide k-step

  const float* xr = x + (size_t)(rowBase + c0) * D_DIM;
  const unsigned short* bph = w1p_hi + lane * 8;   // + (ks*4+t)*512
  const unsigned short* bpl = w1p_lo + lane * 8;

  f32x4 acc[4];
#pragma unroll
  for (int t = 0; t < 4; t++) acc[t] = (f32x4){0.f, 0.f, 0.f, 0.f};

  // double buffers
  float4 a0, a1, na0, na1;
  bf16x8 bfh[4], bfl[4], nbh[4], nbl[4];

  a0 = *reinterpret_cast<const float4*>(xr + kq);
  a1 = *reinterpret_cast<const float4*>(xr + kq + 4);
#pragma unroll
  for (int t = 0; t < 4; t++) {
    bfh[t] = *reinterpret_cast<const bf16x8*>(bph + t * 512);
    bfl[t] = *reinterpret_cast<const bf16x8*>(bpl + t * 512);
  }

  for (int ks = 0; ks < 16; ks++) {
    if (ks < 15) {
      int kb = (ks + 1) * 32;
      na0 = *reinterpret_cast<const float4*>(xr + kb + kq);
      na1 = *reinterpret_cast<const float4*>(xr + kb + kq + 4);
      int fo = (ks + 1) * 4 * 512;
#pragma unroll
      for (int t = 0; t < 4; t++) {
        nbh[t] = *reinterpret_cast<const bf16x8*>(bph + fo + t * 512);
        nbl[t] = *reinterpret_cast<const bf16x8*>(bpl + fo + t * 512);
      }
    }
    bf16x8 afh, afl;
    cvt_hilo(a0, a1, afh, afl);
#pragma unroll
    for (int t = 0; t < 4; t++) {
      acc[t] = __builtin_amdgcn_mfma_f32_16x16x32_bf16(afl, bfh[t], acc[t], 0, 0, 0);
      acc[t] = __builtin_amdgcn_mfma_f32_16x16x32_bf16(afh, bfl[t], acc[t], 0, 0, 0);
      acc[t] = __builtin_amdgcn_mfma_f32_16x16x32_bf16(afh, bfh[t], acc[t], 0, 0, 0);
    }
    a0 = na0; a1 = na1;
#pragma unroll
    for (int t = 0; t < 4; t++) { bfh[t] = nbh[t]; bfl[t] = nbl[t]; }
  }

  // epilogue: h = gelu(acc + ab1); score = h @ aW2 + ab2; w = sigmoid(score)
  float w2v[4], b1v[4];
#pragma unroll
  for (int t = 0; t < 4; t++) {
    w2v[t] = aW2[t * 16 + c0];
    b1v[t] = ab1[t * 16 + c0];
  }
  float bias2 = ab2[0];
  float p[4] = {0.f, 0.f, 0.f, 0.f};
#pragma unroll
  for (int t = 0; t < 4; t++)
#pragma unroll
    for (int r = 0; r < 4; r++) {
      float h = gelu_f(acc[t][r] + b1v[t]);
      p[r] += h * w2v[t];
    }
#pragma unroll
  for (int off = 1; off < 16; off <<= 1)
#pragma unroll
    for (int r = 0; r < 4; r++) p[r] += __shfl_xor(p[r], off, 64);
  if (c0 == 0) {
    int row = rowBase + quad * 4;
#pragma unroll
    for (int r = 0; r < 4; r++) {
      float sc = p[r] + bias2;
      wout[row + r] = 1.0f / (1.0f + expf(-sc));
    }
  }
}

// ---------------- kernel 2: exact top-k threshold per bag ----------------
__global__ __launch_bounds__(256) void k_topk(const float* __restrict__ wout,
                                              unsigned int* __restrict__ meta) {
  int b = blockIdx.x;
  const float* w = wout + b * N_INST;
  int tid = threadIdx.x;
  unsigned int v[32];
#pragma unroll
  for (int j = 0; j < 32; j++) v[j] = __float_as_uint(w[j * 256 + tid]);

  __shared__ int red[2][4];
  int lane = tid & 63, wv = tid >> 6;
  int pb = 0;

  auto blocksum = [&](int c) -> int {
#pragma unroll
    for (int off = 32; off > 0; off >>= 1) c += __shfl_down(c, off, 64);
    if (lane == 0) red[pb][wv] = c;
    __syncthreads();
    int s = red[pb][0] + red[pb][1] + red[pb][2] + red[pb][3];
    pb ^= 1;
    return s;
  };

  // phase 1: largest T with count(bits >= T) >= K (weights in (0,1) -> bits monotone)
  unsigned int lo = 0u, hi = 0x3F800001u;
  while (hi - lo > 1u) {
    unsigned int mid = lo + ((hi - lo) >> 1);
    int c = 0;
#pragma unroll
    for (int j = 0; j < 32; j++) c += (v[j] >= mid) ? 1 : 0;
    int s = blocksum(c);
    if (s >= TOPK_K) lo = mid; else hi = mid;
  }
  unsigned int T = lo;

  // phase 2: count strictly greater
  int c1;
  {
    int c = 0;
#pragma unroll
    for (int j = 0; j < 32; j++) c += (v[j] > T) ? 1 : 0;
    c1 = blocksum(c);
  }
  int needed = TOPK_K - c1;  // >= 1

  // phase 3: smallest m with count(v==T && idx<=m) >= needed, idx = j*256+tid.
  unsigned int tm = 0;
#pragma unroll
  for (int j = 0; j < 32; j++) tm |= (v[j] == T ? 1u : 0u) << j;
  int lom = -1, him = N_INST - 1;
  while (him - lom > 1) {
    int mid = (lom + him) >> 1;
    unsigned int mask = 0u;
    if (mid >= tid) {
      unsigned int jmax = (unsigned int)(mid - tid) >> 8;   // 0..31
      mask = (2u << jmax) - 1u;
    }
    int s = blocksum((int)__popc(tm & mask));
    if (s >= needed) him = mid; else lom = mid;
  }
  if (tid == 0) {
    meta[b] = T;
    ((int*)meta)[8 + b] = him;
  }
}

// ---------------- kernel 3: weighted gather partial sums (float4, 2 rows/iter) ----
__global__ __launch_bounds__(256) void k_gather(const float* __restrict__ x,
                                                const float* __restrict__ wout,
                                                const unsigned int* __restrict__ meta,
                                                float* __restrict__ part3) {
  int b = blockIdx.x >> 6;
  int blk = blockIdx.x & 63;
  unsigned int T = meta[b];
  int Icut = ((const int*)meta)[8 + b];
  int tid = threadIdx.x;

  __shared__ int idxs[128];
  __shared__ float wgts[128];
  __shared__ int wcnt[2];
  __shared__ float4 xfer[128];

  int r = blk * 128 + tid;
  bool sel = false;
  float wvv = 0.f;
  int pos = 0;
  if (tid < 128) {
    wvv = wout[b * N_INST + r];
    unsigned int wu = __float_as_uint(wvv);
    sel = (wu > T) || (wu == T && r <= Icut);
    unsigned long long m = __ballot(sel);
    int lane = tid & 63;
    pos = __popcll(m & ((1ull << lane) - 1ull));
    if (lane == 0) wcnt[tid >> 6] = __popcll(m);
  }
  __syncthreads();
  int total = wcnt[0] + wcnt[1];
  if (sel) {
    int base = (tid >= 64) ? wcnt[0] : 0;
    idxs[base + pos] = r;
    wgts[base + pos] = wvv;
  }
  __syncthreads();

  int half = tid >> 7;      // 0/1: which of the two rows this iteration
  int L = tid & 127;        // 128 lanes x float4 = 512 cols
  float4 acc = {0.f, 0.f, 0.f, 0.f};
  const float* xb = x + (size_t)b * N_INST * D_DIM;
  int i2 = total & ~1;
#pragma unroll 4
  for (int i = 0; i < i2; i += 2) {
    int rr = idxs[i + half];
    float ww = wgts[i + half];
    const float4 xv = *reinterpret_cast<const float4*>(xb + (size_t)rr * D_DIM + L * 4);
    acc.x += ww * xv.x; acc.y += ww * xv.y; acc.z += ww * xv.z; acc.w += ww * xv.w;
  }
  if ((total & 1) && half == 0) {
    int rr = idxs[i2];
    float ww = wgts[i2];
    const float4 xv = *reinterpret_cast<const float4*>(xb + (size_t)rr * D_DIM + L * 4);
    acc.x += ww * xv.x; acc.y += ww * xv.y; acc.z += ww * xv.z; acc.w += ww * xv.w;
  }
  if (half == 1) xfer[L] = acc;
  __syncthreads();
  if (half == 0) {
    float4 o = xfer[L];
    acc.x += o.x; acc.y += o.y; acc.z += o.z; acc.w += o.w;
    *reinterpret_cast<float4*>(part3 + (size_t)(b * 64 + blk) * D_DIM + L * 4) = acc;
  }
}

// ---------------- projection MLP: split-K, 64 blocks per layer ----------------
__global__ __launch_bounds__(256) void k_proj1(const float* __restrict__ part3,
                                               const float* __restrict__ pW1,
                                               float* __restrict__ part1) {
  int jt = blockIdx.x & 7, kt = blockIdx.x >> 3;
  __shared__ float emb_s[512];   // [b*64 + d0], d = kt*64 + d0
  int tid = threadIdx.x;
#pragma unroll
  for (int h = 0; h < 2; h++) {
    int vi = tid + h * 256;
    int b = vi >> 6, d0 = vi & 63;
    const float* p = part3 + (size_t)b * 64 * 512 + kt * 64 + d0;
    float e = 0.f;
#pragma unroll 8
    for (int j = 0; j < 64; j++) e += p[j * 512];
    emb_s[vi] = e * (1.0f / TOPK_K);
  }
  __syncthreads();
  int col = tid & 63, bg = tid >> 6;   // bags bg*2, bg*2+1
  float a0 = 0.f, a1 = 0.f;
  const float* wrow = pW1 + (size_t)(kt * 64) * 512 + jt * 64 + col;
#pragma unroll 8
  for (int q = 0; q < 64; q++) {
    float wq = wrow[q * 512];
    a0 += emb_s[(bg * 2) * 64 + q] * wq;
    a1 += emb_s[(bg * 2 + 1) * 64 + q] * wq;
  }
  part1[kt * 4096 + (bg * 2) * 512 + jt * 64 + col] = a0;
  part1[kt * 4096 + (bg * 2 + 1) * 512 + jt * 64 + col] = a1;
}

__global__ __launch_bounds__(256) void k_proj2(const float* __restrict__ part1,
                                               const float* __restrict__ pb1,
                                               const float* __restrict__ pW2,
                                               float* __restrict__ part2) {
  int jt = blockIdx.x & 7, kt = blockIdx.x >> 3;
  __shared__ float h_s[512];   // [b*64 + j0], j = kt*64 + j0
  int tid = threadIdx.x;
#pragma unroll
  for (int h = 0; h < 2; h++) {
    int vi = tid + h * 256;
    int b = vi >> 6, j0 = vi & 63;
    int jj = kt * 64 + j0;
    float s = pb1[jj];
#pragma unroll
    for (int p = 0; p < 8; p++) s += part1[p * 4096 + b * 512 + jj];
    h_s[vi] = gelu_f(s);
  }
  __syncthreads();
  int col = tid & 63, bg = tid >> 6;
  float a0 = 0.f, a1 = 0.f;
  const float* wrow = pW2 + (size_t)(kt * 64) * 512 + jt * 64 + col;
#pragma unroll 8
  for (int q = 0; q < 64; q++) {
    float wq = wrow[q * 512];
    a0 += h_s[(bg * 2) * 64 + q] * wq;
    a1 += h_s[(bg * 2 + 1) * 64 + q] * wq;
  }
  part2[kt * 4096 + (bg * 2) * 512 + jt * 64 + col] = a0;
  part2[kt * 4096 + (bg * 2 + 1) * 512 + jt * 64 + col] = a1;
}

__global__ __launch_bounds__(512) void k_proj3(const float* __restrict__ part2,
                                               const float* __restrict__ pb2,
                                               float* __restrict__ out) {
  int o = blockIdx.x * 512 + threadIdx.x;   // o = b*512 + j
  int bj = o & 511;
  float s = pb2[bj];
#pragma unroll
  for (int p = 0; p < 8; p++) s += part2[p * 4096 + o];
  out[o] = s;
}

extern "C" void kernel_launch(void* const* d_in, const int* in_sizes, int n_in,
                              void* d_out, int out_size, void* d_ws, size_t ws_size,
                              hipStream_t stream) {
  (void)in_sizes; (void)n_in; (void)out_size; (void)ws_size;
  const float* x   = (const float*)d_in[0];
  const float* aW1 = (const float*)d_in[1];
  const float* ab1 = (const float*)d_in[2];
  const float* aW2 = (const float*)d_in[3];
  const float* ab2 = (const float*)d_in[4];
  const float* pW1 = (const float*)d_in[5];
  const float* pb1 = (const float*)d_in[6];
  const float* pW2 = (const float*)d_in[7];
  const float* pb2 = (const float*)d_in[8];

  float* out  = (float*)d_out;
  float* wout = out + B_BAGS * D_DIM;  // weights output region [8][8192]

  char* ws = (char*)d_ws;
  unsigned short* w1p_hi = (unsigned short*)(ws + WS_W1P_HI);
  unsigned short* w1p_lo = (unsigned short*)(ws + WS_W1P_LO);
  unsigned int*   meta   = (unsigned int*)(ws + WS_META);
  float* part3 = (float*)(ws + WS_PART3);
  float* part1 = (float*)(ws + WS_PART1);
  float* part2 = (float*)(ws + WS_PART2);

  k_prep<<<dim3(16), dim3(256), 0, stream>>>(aW1, w1p_hi, w1p_lo);
  k_scores<<<dim3(ROWS_TOTAL / BM), dim3(256), 0, stream>>>(x, w1p_hi, w1p_lo, ab1, aW2, ab2, wout);
  k_topk<<<dim3(B_BAGS), dim3(256), 0, stream>>>(wout, meta);
  k_gather<<<dim3(B_BAGS * 64), dim3(256), 0, stream>>>(x, wout, meta, part3);
  k_proj1<<<dim3(64), dim3(256), 0, stream>>>(part3, pW1, part1);
  k_proj2<<<dim3(64), dim3(256), 0, stream>>>(part1, pb1, pW2, part2);
  k_proj3<<<dim3(B_BAGS), dim3(512), 0, stream>>>(part2, pb2, out);
}

// Round 7
// 265.549 us; speedup vs baseline: 1.4273x; 1.0234x over previous
//
#include <hip/hip_runtime.h>
#include <math.h>

#define B_BAGS 8
#define N_INST 8192
#define D_DIM  512
#define H_ATT  64
#define TOPK_K 2457
#define ROWS_TOTAL (B_BAGS * N_INST)

typedef __attribute__((ext_vector_type(8))) short bf16x8;
typedef __attribute__((ext_vector_type(4))) float f32x4;

// ---- workspace layout (bytes) ----
#define WS_W1P_HI 0                          // packed MFMA B-frags, 32768 ushort
#define WS_W1P_LO 65536                      // packed MFMA B-frags, 32768 ushort
#define WS_PART3  131584                     // [8][64][512] f32 gather partials (1 MB)
#define WS_PART1  (WS_PART3 + 8*64*512*4)    // [8kt][8b][512] f32 layer1 partials

__device__ __forceinline__ unsigned short bf16_rn(float f) {
  unsigned int x = __float_as_uint(f);
  unsigned int r = (x + 0x7FFFu + ((x >> 16) & 1u)) >> 16;
  return (unsigned short)r;
}
__device__ __forceinline__ float bf16_f(unsigned short u) {
  return __uint_as_float(((unsigned int)u) << 16);
}
__device__ __forceinline__ float gelu_f(float v) {
  float u = 0.7978845608028654f * (v + 0.044715f * v * v * v);
  return 0.5f * v * (1.0f + tanhf(u));
}

// truncation-based hi/lo split of 8 consecutive fp32 -> bf16x8 hi + lo.
__device__ __forceinline__ void cvt_hilo(const float4 u, const float4 v,
                                         bf16x8& h, bf16x8& l) {
  float f[8] = {u.x, u.y, u.z, u.w, v.x, v.y, v.z, v.w};
#pragma unroll
  for (int i = 0; i < 8; i++) {
    unsigned int b = __float_as_uint(f[i]);
    unsigned int hb = b & 0xFFFF0000u;
    float r = f[i] - __uint_as_float(hb);
    h[i] = (short)(b >> 16);
    l[i] = (short)(__float_as_uint(r) >> 16);
  }
}

// ---------------- kernel 0: pack aW1 into MFMA-fragment-sequential layout ----
// Packed at offset ((ks*4 + t)*64 + lane)*8 + j -> hot-loop B loads are
// base + lane*16B: fully coalesced (1 line-txn per instr).
__global__ __launch_bounds__(256) void k_prep(const float* __restrict__ aW1,
                                              unsigned short* __restrict__ hi,
                                              unsigned short* __restrict__ lo) {
  int tau = blockIdx.x * 256 + threadIdx.x;   // (ks,t,lane) tuple, 4096 total
  if (tau >= 4096) return;
  int ks = tau >> 8, t = (tau >> 6) & 3, lane = tau & 63;
  int n = t * 16 + (lane & 15);
  int kb = ks * 32 + (lane >> 4) * 8;
#pragma unroll
  for (int j = 0; j < 8; j++) {
    float v = aW1[(kb + j) * H_ATT + n];
    unsigned short h = bf16_rn(v);
    unsigned short l = bf16_rn(v - bf16_f(h));
    hi[tau * 8 + j] = h;
    lo[tau * 8 + j] = l;
  }
}

// ---------------- kernel 1: score MLP -> sigmoid weights ----------------
// No LDS, no barriers. 512 blocks x 128 rows (2 blocks/CU): each wave owns
// 32 rows (2 row-tiles) -> 24 MFMA per k-step per wave, B L2 traffic halved
// vs BM=64. A and B register-double-buffered one k-step ahead.
#define BM 128

__global__ __launch_bounds__(256) void k_scores(
    const float* __restrict__ x,
    const unsigned short* __restrict__ w1p_hi,
    const unsigned short* __restrict__ w1p_lo,
    const float* __restrict__ ab1, const float* __restrict__ aW2,
    const float* __restrict__ ab2, float* __restrict__ wout) {
  int tid = threadIdx.x;
  int wave = tid >> 6, lane = tid & 63;
  int c0 = lane & 15, quad = lane >> 4;
  int rowBase = blockIdx.x * BM + wave * 32;
  const int kq = quad * 8;   // lane's k offset within a 32-wide k-step

  const float* xr[2];
  xr[0] = x + (size_t)(rowBase + c0) * D_DIM;
  xr[1] = xr[0] + 16 * D_DIM;
  const unsigned short* bph = w1p_hi + lane * 8;   // + (ks*4+t)*512
  const unsigned short* bpl = w1p_lo + lane * 8;

  f32x4 acc[2][4];
#pragma unroll
  for (int s = 0; s < 2; s++)
#pragma unroll
    for (int t = 0; t < 4; t++) acc[s][t] = (f32x4){0.f, 0.f, 0.f, 0.f};

  // double buffers
  float4 a0[2], a1[2], na0[2], na1[2];
  bf16x8 bfh[4], bfl[4], nbh[4], nbl[4];

#pragma unroll
  for (int s = 0; s < 2; s++) {
    a0[s] = *reinterpret_cast<const float4*>(xr[s] + kq);
    a1[s] = *reinterpret_cast<const float4*>(xr[s] + kq + 4);
  }
#pragma unroll
  for (int t = 0; t < 4; t++) {
    bfh[t] = *reinterpret_cast<const bf16x8*>(bph + t * 512);
    bfl[t] = *reinterpret_cast<const bf16x8*>(bpl + t * 512);
  }

  for (int ks = 0; ks < 16; ks++) {
    if (ks < 15) {
      int kb = (ks + 1) * 32;
#pragma unroll
      for (int s = 0; s < 2; s++) {
        na0[s] = *reinterpret_cast<const float4*>(xr[s] + kb + kq);
        na1[s] = *reinterpret_cast<const float4*>(xr[s] + kb + kq + 4);
      }
      int fo = (ks + 1) * 4 * 512;
#pragma unroll
      for (int t = 0; t < 4; t++) {
        nbh[t] = *reinterpret_cast<const bf16x8*>(bph + fo + t * 512);
        nbl[t] = *reinterpret_cast<const bf16x8*>(bpl + fo + t * 512);
      }
    }
    bf16x8 afh[2], afl[2];
#pragma unroll
    for (int s = 0; s < 2; s++) cvt_hilo(a0[s], a1[s], afh[s], afl[s]);
#pragma unroll
    for (int s = 0; s < 2; s++)
#pragma unroll
      for (int t = 0; t < 4; t++) {
        acc[s][t] = __builtin_amdgcn_mfma_f32_16x16x32_bf16(afl[s], bfh[t], acc[s][t], 0, 0, 0);
        acc[s][t] = __builtin_amdgcn_mfma_f32_16x16x32_bf16(afh[s], bfl[t], acc[s][t], 0, 0, 0);
        acc[s][t] = __builtin_amdgcn_mfma_f32_16x16x32_bf16(afh[s], bfh[t], acc[s][t], 0, 0, 0);
      }
#pragma unroll
    for (int s = 0; s < 2; s++) { a0[s] = na0[s]; a1[s] = na1[s]; }
#pragma unroll
    for (int t = 0; t < 4; t++) { bfh[t] = nbh[t]; bfl[t] = nbl[t]; }
  }

  // epilogue: h = gelu(acc + ab1); score = h @ aW2 + ab2; w = sigmoid(score)
  float w2v[4], b1v[4];
#pragma unroll
  for (int t = 0; t < 4; t++) {
    w2v[t] = aW2[t * 16 + c0];
    b1v[t] = ab1[t * 16 + c0];
  }
  float bias2 = ab2[0];
#pragma unroll
  for (int s = 0; s < 2; s++) {
    float p[4] = {0.f, 0.f, 0.f, 0.f};
#pragma unroll
    for (int t = 0; t < 4; t++)
#pragma unroll
      for (int r = 0; r < 4; r++) {
        float h = gelu_f(acc[s][t][r] + b1v[t]);
        p[r] += h * w2v[t];
      }
#pragma unroll
    for (int off = 1; off < 16; off <<= 1)
#pragma unroll
      for (int r = 0; r < 4; r++) p[r] += __shfl_xor(p[r], off, 64);
    if (c0 == 0) {
      int row = rowBase + s * 16 + quad * 4;
#pragma unroll
      for (int r = 0; r < 4; r++) {
        float sc = p[r] + bias2;
        wout[row + r] = 1.0f / (1.0f + expf(-sc));
      }
    }
  }
}

// ---------------- kernel 2: fused top-k + weighted gather ----------------
// Each of the 512 blocks redundantly computes its bag's exact threshold
// (bit-space binary search over register-held weights), then gathers its
// 128-row slice. No meta round-trip, no extra kernel.
__global__ __launch_bounds__(256) void k_gather(const float* __restrict__ x,
                                                const float* __restrict__ wout,
                                                float* __restrict__ part3) {
  int b = blockIdx.x >> 6;
  int blk = blockIdx.x & 63;
  int tid = threadIdx.x;
  const float* w = wout + b * N_INST;

  unsigned int v[32];
#pragma unroll
  for (int j = 0; j < 32; j++) v[j] = __float_as_uint(w[j * 256 + tid]);

  __shared__ int red[2][4];
  int lane = tid & 63, wv = tid >> 6;
  int pb = 0;
  auto blocksum = [&](int c) -> int {
#pragma unroll
    for (int off = 32; off > 0; off >>= 1) c += __shfl_down(c, off, 64);
    if (lane == 0) red[pb][wv] = c;
    __syncthreads();
    int s = red[pb][0] + red[pb][1] + red[pb][2] + red[pb][3];
    pb ^= 1;
    return s;
  };

  // phase 1: largest T with count(bits >= T) >= K
  unsigned int lo = 0u, hi = 0x3F800001u;
  while (hi - lo > 1u) {
    unsigned int mid = lo + ((hi - lo) >> 1);
    int c = 0;
#pragma unroll
    for (int j = 0; j < 32; j++) c += (v[j] >= mid) ? 1 : 0;
    if (blocksum(c) >= TOPK_K) lo = mid; else hi = mid;
  }
  unsigned int T = lo;
  // phase 2: count strictly greater
  int c1 = 0;
#pragma unroll
  for (int j = 0; j < 32; j++) c1 += (v[j] > T) ? 1 : 0;
  c1 = blocksum(c1);
  int needed = TOPK_K - c1;  // >= 1
  // phase 3: smallest m with count(v==T && idx<=m) >= needed, idx=j*256+tid
  unsigned int tm = 0;
#pragma unroll
  for (int j = 0; j < 32; j++) tm |= (v[j] == T ? 1u : 0u) << j;
  int lom = -1, him = N_INST - 1;
  while (him - lom > 1) {
    int mid = (lom + him) >> 1;
    unsigned int mask = 0u;
    if (mid >= tid) {
      unsigned int jmax = (unsigned int)(mid - tid) >> 8;
      mask = (2u << jmax) - 1u;
    }
    if (blocksum((int)__popc(tm & mask)) >= needed) him = mid; else lom = mid;
  }
  int Icut = him;

  // ---- gather this block's 128-row slice ----
  __shared__ int idxs[128];
  __shared__ float wgts[128];
  __shared__ int wcnt[2];
  __shared__ float4 xfer[128];

  int r = blk * 128 + tid;
  bool sel = false;
  float wvv = 0.f;
  int pos = 0;
  if (tid < 128) {
    wvv = w[r];
    unsigned int wu = __float_as_uint(wvv);
    sel = (wu > T) || (wu == T && r <= Icut);
    unsigned long long m = __ballot(sel);
    pos = __popcll(m & ((1ull << lane) - 1ull));
    if (lane == 0) wcnt[tid >> 6] = __popcll(m);
  }
  __syncthreads();
  int total = wcnt[0] + wcnt[1];
  if (sel) {
    int base = (tid >= 64) ? wcnt[0] : 0;
    idxs[base + pos] = r;
    wgts[base + pos] = wvv;
  }
  __syncthreads();

  int half = tid >> 7;      // 0/1: which of the two rows this iteration
  int L = tid & 127;        // 128 lanes x float4 = 512 cols
  float4 acc = {0.f, 0.f, 0.f, 0.f};
  const float* xb = x + (size_t)b * N_INST * D_DIM;
  int i2 = total & ~1;
#pragma unroll 4
  for (int i = 0; i < i2; i += 2) {
    int rr = idxs[i + half];
    float ww = wgts[i + half];
    const float4 xv = *reinterpret_cast<const float4*>(xb + (size_t)rr * D_DIM + L * 4);
    acc.x += ww * xv.x; acc.y += ww * xv.y; acc.z += ww * xv.z; acc.w += ww * xv.w;
  }
  if ((total & 1) && half == 0) {
    int rr = idxs[i2];
    float ww = wgts[i2];
    const float4 xv = *reinterpret_cast<const float4*>(xb + (size_t)rr * D_DIM + L * 4);
    acc.x += ww * xv.x; acc.y += ww * xv.y; acc.z += ww * xv.z; acc.w += ww * xv.w;
  }
  if (half == 1) xfer[L] = acc;
  __syncthreads();
  if (half == 0) {
    float4 o = xfer[L];
    acc.x += o.x; acc.y += o.y; acc.z += o.z; acc.w += o.w;
    *reinterpret_cast<float4*>(part3 + (size_t)(b * 64 + blk) * D_DIM + L * 4) = acc;
  }
}

// ---------------- projection MLP: split-K; layer2 accumulates into out ----
__global__ __launch_bounds__(256) void k_proj1(const float* __restrict__ part3,
                                               const float* __restrict__ pW1,
                                               float* __restrict__ part1,
                                               const float* __restrict__ pb2,
                                               float* __restrict__ out) {
  int jt = blockIdx.x & 7, kt = blockIdx.x >> 3;
  __shared__ float emb_s[512];   // [b*64 + d0], d = kt*64 + d0
  int tid = threadIdx.x;
  int col = tid & 63, bg = tid >> 6;
  // init out with pb2 (kt==0 blocks); proj2's atomics add onto this
  if (kt == 0) {
    float bz = pb2[jt * 64 + col];
    out[(bg * 2) * 512 + jt * 64 + col] = bz;
    out[(bg * 2 + 1) * 512 + jt * 64 + col] = bz;
  }
#pragma unroll
  for (int h = 0; h < 2; h++) {
    int vi = tid + h * 256;
    int b = vi >> 6, d0 = vi & 63;
    const float* p = part3 + (size_t)b * 64 * 512 + kt * 64 + d0;
    float e = 0.f;
#pragma unroll 8
    for (int j = 0; j < 64; j++) e += p[j * 512];
    emb_s[vi] = e * (1.0f / TOPK_K);
  }
  __syncthreads();
  float a0 = 0.f, a1 = 0.f;
  const float* wrow = pW1 + (size_t)(kt * 64) * 512 + jt * 64 + col;
#pragma unroll 8
  for (int q = 0; q < 64; q++) {
    float wq = wrow[q * 512];
    a0 += emb_s[(bg * 2) * 64 + q] * wq;
    a1 += emb_s[(bg * 2 + 1) * 64 + q] * wq;
  }
  part1[kt * 4096 + (bg * 2) * 512 + jt * 64 + col] = a0;
  part1[kt * 4096 + (bg * 2 + 1) * 512 + jt * 64 + col] = a1;
}

__global__ __launch_bounds__(256) void k_proj2(const float* __restrict__ part1,
                                               const float* __restrict__ pb1,
                                               const float* __restrict__ pW2,
                                               float* __restrict__ out) {
  int jt = blockIdx.x & 7, kt = blockIdx.x >> 3;
  __shared__ float h_s[512];   // [b*64 + j0], j = kt*64 + j0
  int tid = threadIdx.x;
#pragma unroll
  for (int h = 0; h < 2; h++) {
    int vi = tid + h * 256;
    int b = vi >> 6, j0 = vi & 63;
    int jj = kt * 64 + j0;
    float s = pb1[jj];
#pragma unroll
    for (int p = 0; p < 8; p++) s += part1[p * 4096 + b * 512 + jj];
    h_s[vi] = gelu_f(s);
  }
  __syncthreads();
  int col = tid & 63, bg = tid >> 6;
  float a0 = 0.f, a1 = 0.f;
  const float* wrow = pW2 + (size_t)(kt * 64) * 512 + jt * 64 + col;
#pragma unroll 8
  for (int q = 0; q < 64; q++) {
    float wq = wrow[q * 512];
    a0 += h_s[(bg * 2) * 64 + q] * wq;
    a1 += h_s[(bg * 2 + 1) * 64 + q] * wq;
  }
  atomicAdd(&out[(bg * 2) * 512 + jt * 64 + col], a0);
  atomicAdd(&out[(bg * 2 + 1) * 512 + jt * 64 + col], a1);
}

extern "C" void kernel_launch(void* const* d_in, const int* in_sizes, int n_in,
                              void* d_out, int out_size, void* d_ws, size_t ws_size,
                              hipStream_t stream) {
  (void)in_sizes; (void)n_in; (void)out_size; (void)ws_size;
  const float* x   = (const float*)d_in[0];
  const float* aW1 = (const float*)d_in[1];
  const float* ab1 = (const float*)d_in[2];
  const float* aW2 = (const float*)d_in[3];
  const float* ab2 = (const float*)d_in[4];
  const float* pW1 = (const float*)d_in[5];
  const float* pb1 = (const float*)d_in[6];
  const float* pW2 = (const float*)d_in[7];
  const float* pb2 = (const float*)d_in[8];

  float* out  = (float*)d_out;
  float* wout = out + B_BAGS * D_DIM;  // weights output region [8][8192]

  char* ws = (char*)d_ws;
  unsigned short* w1p_hi = (unsigned short*)(ws + WS_W1P_HI);
  unsigned short* w1p_lo = (unsigned short*)(ws + WS_W1P_LO);
  float* part3 = (float*)(ws + WS_PART3);
  float* part1 = (float*)(ws + WS_PART1);

  k_prep<<<dim3(16), dim3(256), 0, stream>>>(aW1, w1p_hi, w1p_lo);
  k_scores<<<dim3(ROWS_TOTAL / BM), dim3(256), 0, stream>>>(x, w1p_hi, w1p_lo, ab1, aW2, ab2, wout);
  k_gather<<<dim3(B_BAGS * 64), dim3(256), 0, stream>>>(x, wout, part3);
  k_proj1<<<dim3(64), dim3(256), 0, stream>>>(part3, pW1, part1, pb2, out);
  k_proj2<<<dim3(64), dim3(256), 0, stream>>>(part1, pb1, pW2, out);
}

// Round 8
// 259.182 us; speedup vs baseline: 1.4624x; 1.0246x over previous
//
#include <hip/hip_runtime.h>
#include <math.h>

#define B_BAGS 8
#define N_INST 8192
#define D_DIM  512
#define H_ATT  64
#define TOPK_K 2457
#define ROWS_TOTAL (B_BAGS * N_INST)

typedef __attribute__((ext_vector_type(8))) short bf16x8;
typedef __attribute__((ext_vector_type(4))) float f32x4;

// ---- workspace layout (bytes) ----
#define WS_W1P_HI 0                          // packed MFMA B-frags, 32768 ushort
#define WS_W1P_LO 65536                      // packed MFMA B-frags, 32768 ushort
#define WS_PART3  131584                     // [8][64][512] f32 gather partials (1 MB)
#define WS_PART1  (WS_PART3 + 8*64*512*4)    // [8kt][8b][512] f32 layer1 partials

__device__ __forceinline__ unsigned short bf16_rn(float f) {
  unsigned int x = __float_as_uint(f);
  unsigned int r = (x + 0x7FFFu + ((x >> 16) & 1u)) >> 16;
  return (unsigned short)r;
}
__device__ __forceinline__ float bf16_f(unsigned short u) {
  return __uint_as_float(((unsigned int)u) << 16);
}
__device__ __forceinline__ float gelu_f(float v) {
  float u = 0.7978845608028654f * (v + 0.044715f * v * v * v);
  return 0.5f * v * (1.0f + tanhf(u));
}

// truncation-based hi/lo split of 8 consecutive fp32 -> bf16x8 hi + lo.
__device__ __forceinline__ void cvt_hilo(const float4 u, const float4 v,
                                         bf16x8& h, bf16x8& l) {
  float f[8] = {u.x, u.y, u.z, u.w, v.x, v.y, v.z, v.w};
#pragma unroll
  for (int i = 0; i < 8; i++) {
    unsigned int b = __float_as_uint(f[i]);
    unsigned int hb = b & 0xFFFF0000u;
    float r = f[i] - __uint_as_float(hb);
    h[i] = (short)(b >> 16);
    l[i] = (short)(__float_as_uint(r) >> 16);
  }
}

// async global->LDS DMA, 16B per lane. LDS dest = wave-uniform base + lane*16.
__device__ __forceinline__ void load_lds16(const void* g, void* l) {
  __builtin_amdgcn_global_load_lds(
      (const __attribute__((address_space(1))) void*)g,
      (__attribute__((address_space(3))) void*)l, 16, 0, 0);
}

// ---------------- kernel 0: pack aW1 into MFMA-fragment-sequential layout ----
// Packed at offset ((ks*4 + t)*64 + lane)*8 + j -> B loads are lane-linear.
__global__ __launch_bounds__(256) void k_prep(const float* __restrict__ aW1,
                                              unsigned short* __restrict__ hi,
                                              unsigned short* __restrict__ lo) {
  int tau = blockIdx.x * 256 + threadIdx.x;   // (ks,t,lane) tuple, 4096 total
  if (tau >= 4096) return;
  int ks = tau >> 8, t = (tau >> 6) & 3, lane = tau & 63;
  int n = t * 16 + (lane & 15);
  int kb = ks * 32 + (lane >> 4) * 8;
#pragma unroll
  for (int j = 0; j < 8; j++) {
    float v = aW1[(kb + j) * H_ATT + n];
    unsigned short h = bf16_rn(v);
    unsigned short l = bf16_rn(v - bf16_f(h));
    hi[tau * 8 + j] = h;
    lo[tau * 8 + j] = l;
  }
}

// ---------------- kernel 1: score MLP -> sigmoid weights ----------------
// m97-style: global_load_lds staging (no dest VGPRs -> loads can't be
// serialized by register reuse; all 32 chunk-loads in flight at once,
// drained by one __syncthreads). BM=64 rows/block, K-chunk=64.
// A LDS: 16 units of 1KB (4 rows x 256B) with 16B inter-unit pad ->
// fragment ds_read_b128 pattern hits the 8-access/bank floor (no conflicts).
// B LDS: staged in packed layout, lane-linear reads (conflict-free).
#define BM 64
#define AUNIT 1040   // 1024 + 16B pad

__global__ __launch_bounds__(256) void k_scores(
    const float* __restrict__ x,
    const unsigned short* __restrict__ w1p_hi,
    const unsigned short* __restrict__ w1p_lo,
    const float* __restrict__ ab1, const float* __restrict__ aW2,
    const float* __restrict__ ab2, float* __restrict__ wout) {
  __shared__ __align__(16) char Asm[16 * AUNIT];
  __shared__ __align__(16) char Bh[8192];
  __shared__ __align__(16) char Bl[8192];

  int tid = threadIdx.x;
  int wave = tid >> 6, lane = tid & 63;
  int c0 = lane & 15, quad = lane >> 4;
  int rowBase0 = blockIdx.x * BM;

  f32x4 acc[4];
#pragma unroll
  for (int t = 0; t < 4; t++) acc[t] = (f32x4){0.f, 0.f, 0.f, 0.f};

  const int r = wave * 16 + c0;        // row within block this lane computes
  const int uA = r >> 2;
  const int aoff = uA * AUNIT + (r & 3) * 256 + quad * 32;

  for (int c = 0; c < 8; c++) {
    // ---- stage chunk c: A 16KB (16 instr) + B 16KB (16 instr), 8/wave ----
    size_t kb = (size_t)c * 256;   // byte offset within a row
#pragma unroll
    for (int i = 0; i < 4; i++) {
      int u = wave * 4 + i;
      const char* g = (const char*)x +
          (size_t)(rowBase0 + u * 4 + (lane >> 4)) * 2048 + kb + (size_t)(lane & 15) * 16;
      load_lds16(g, Asm + u * AUNIT);
    }
#pragma unroll
    for (int i = 0; i < 4; i++) {
      int v = wave * 4 + i;    // 0..15: 0-7 hi, 8-15 lo
      int vv = v & 7;
      const char* gsrc = (v < 8) ? (const char*)w1p_hi : (const char*)w1p_lo;
      char* ldst = (v < 8) ? Bh : Bl;
      load_lds16(gsrc + (size_t)c * 8192 + vv * 1024 + (size_t)lane * 16,
                 ldst + vv * 1024);
    }
    __syncthreads();   // drains DMA (vmcnt) + makes LDS visible

    // ---- compute chunk c: 2 k-steps ----
#pragma unroll
    for (int stp = 0; stp < 2; stp++) {
      const float4 a0v = *reinterpret_cast<const float4*>(Asm + aoff + stp * 128);
      const float4 a1v = *reinterpret_cast<const float4*>(Asm + aoff + stp * 128 + 16);
      bf16x8 afh, afl;
      cvt_hilo(a0v, a1v, afh, afl);
      bf16x8 bfh[4], bfl[4];
#pragma unroll
      for (int t = 0; t < 4; t++) {
        bfh[t] = *reinterpret_cast<const bf16x8*>(Bh + (stp * 4 + t) * 1024 + lane * 16);
        bfl[t] = *reinterpret_cast<const bf16x8*>(Bl + (stp * 4 + t) * 1024 + lane * 16);
      }
#pragma unroll
      for (int t = 0; t < 4; t++) {
        acc[t] = __builtin_amdgcn_mfma_f32_16x16x32_bf16(afl, bfh[t], acc[t], 0, 0, 0);
        acc[t] = __builtin_amdgcn_mfma_f32_16x16x32_bf16(afh, bfl[t], acc[t], 0, 0, 0);
        acc[t] = __builtin_amdgcn_mfma_f32_16x16x32_bf16(afh, bfh[t], acc[t], 0, 0, 0);
      }
    }
    __syncthreads();   // protect LDS before next chunk overwrites
  }

  // epilogue: h = gelu(acc + ab1); score = h @ aW2 + ab2; w = sigmoid(score)
  float w2v[4], b1v[4];
#pragma unroll
  for (int t = 0; t < 4; t++) {
    w2v[t] = aW2[t * 16 + c0];
    b1v[t] = ab1[t * 16 + c0];
  }
  float bias2 = ab2[0];
  float p[4] = {0.f, 0.f, 0.f, 0.f};
#pragma unroll
  for (int t = 0; t < 4; t++)
#pragma unroll
    for (int rr = 0; rr < 4; rr++) {
      float h = gelu_f(acc[t][rr] + b1v[t]);
      p[rr] += h * w2v[t];
    }
#pragma unroll
  for (int off = 1; off < 16; off <<= 1)
#pragma unroll
    for (int rr = 0; rr < 4; rr++) p[rr] += __shfl_xor(p[rr], off, 64);
  if (c0 == 0) {
    int row = rowBase0 + wave * 16 + quad * 4;
#pragma unroll
    for (int rr = 0; rr < 4; rr++) {
      float sc = p[rr] + bias2;
      wout[row + rr] = 1.0f / (1.0f + expf(-sc));
    }
  }
}

// ---------------- kernel 2: fused top-k + weighted gather ----------------
__global__ __launch_bounds__(256) void k_gather(const float* __restrict__ x,
                                                const float* __restrict__ wout,
                                                float* __restrict__ part3) {
  int b = blockIdx.x >> 6;
  int blk = blockIdx.x & 63;
  int tid = threadIdx.x;
  const float* w = wout + b * N_INST;

  unsigned int v[32];
#pragma unroll
  for (int j = 0; j < 32; j++) v[j] = __float_as_uint(w[j * 256 + tid]);

  __shared__ int red[2][4];
  int lane = tid & 63, wv = tid >> 6;
  int pb = 0;
  auto blocksum = [&](int c) -> int {
#pragma unroll
    for (int off = 32; off > 0; off >>= 1) c += __shfl_down(c, off, 64);
    if (lane == 0) red[pb][wv] = c;
    __syncthreads();
    int s = red[pb][0] + red[pb][1] + red[pb][2] + red[pb][3];
    pb ^= 1;
    return s;
  };

  unsigned int lo = 0u, hi = 0x3F800001u;
  while (hi - lo > 1u) {
    unsigned int mid = lo + ((hi - lo) >> 1);
    int c = 0;
#pragma unroll
    for (int j = 0; j < 32; j++) c += (v[j] >= mid) ? 1 : 0;
    if (blocksum(c) >= TOPK_K) lo = mid; else hi = mid;
  }
  unsigned int T = lo;
  int c1 = 0;
#pragma unroll
  for (int j = 0; j < 32; j++) c1 += (v[j] > T) ? 1 : 0;
  c1 = blocksum(c1);
  int needed = TOPK_K - c1;  // >= 1
  unsigned int tm = 0;
#pragma unroll
  for (int j = 0; j < 32; j++) tm |= (v[j] == T ? 1u : 0u) << j;
  int lom = -1, him = N_INST - 1;
  while (him - lom > 1) {
    int mid = (lom + him) >> 1;
    unsigned int mask = 0u;
    if (mid >= tid) {
      unsigned int jmax = (unsigned int)(mid - tid) >> 8;
      mask = (2u << jmax) - 1u;
    }
    if (blocksum((int)__popc(tm & mask)) >= needed) him = mid; else lom = mid;
  }
  int Icut = him;

  __shared__ int idxs[128];
  __shared__ float wgts[128];
  __shared__ int wcnt[2];
  __shared__ float4 xfer[128];

  int r = blk * 128 + tid;
  bool sel = false;
  float wvv = 0.f;
  int pos = 0;
  if (tid < 128) {
    wvv = w[r];
    unsigned int wu = __float_as_uint(wvv);
    sel = (wu > T) || (wu == T && r <= Icut);
    unsigned long long m = __ballot(sel);
    pos = __popcll(m & ((1ull << lane) - 1ull));
    if (lane == 0) wcnt[tid >> 6] = __popcll(m);
  }
  __syncthreads();
  int total = wcnt[0] + wcnt[1];
  if (sel) {
    int base = (tid >= 64) ? wcnt[0] : 0;
    idxs[base + pos] = r;
    wgts[base + pos] = wvv;
  }
  __syncthreads();

  int half = tid >> 7;
  int L = tid & 127;
  float4 acc = {0.f, 0.f, 0.f, 0.f};
  const float* xb = x + (size_t)b * N_INST * D_DIM;
  int i2 = total & ~1;
#pragma unroll 4
  for (int i = 0; i < i2; i += 2) {
    int rr = idxs[i + half];
    float ww = wgts[i + half];
    const float4 xv = *reinterpret_cast<const float4*>(xb + (size_t)rr * D_DIM + L * 4);
    acc.x += ww * xv.x; acc.y += ww * xv.y; acc.z += ww * xv.z; acc.w += ww * xv.w;
  }
  if ((total & 1) && half == 0) {
    int rr = idxs[i2];
    float ww = wgts[i2];
    const float4 xv = *reinterpret_cast<const float4*>(xb + (size_t)rr * D_DIM + L * 4);
    acc.x += ww * xv.x; acc.y += ww * xv.y; acc.z += ww * xv.z; acc.w += ww * xv.w;
  }
  if (half == 1) xfer[L] = acc;
  __syncthreads();
  if (half == 0) {
    float4 o = xfer[L];
    acc.x += o.x; acc.y += o.y; acc.z += o.z; acc.w += o.w;
    *reinterpret_cast<float4*>(part3 + (size_t)(b * 64 + blk) * D_DIM + L * 4) = acc;
  }
}

// ---------------- projection MLP: split-K; layer2 accumulates into out ----
__global__ __launch_bounds__(256) void k_proj1(const float* __restrict__ part3,
                                               const float* __restrict__ pW1,
                                               float* __restrict__ part1,
                                               const float* __restrict__ pb2,
                                               float* __restrict__ out) {
  int jt = blockIdx.x & 7, kt = blockIdx.x >> 3;
  __shared__ float emb_s[512];
  int tid = threadIdx.x;
  int col = tid & 63, bg = tid >> 6;
  if (kt == 0) {
    float bz = pb2[jt * 64 + col];
    out[(bg * 2) * 512 + jt * 64 + col] = bz;
    out[(bg * 2 + 1) * 512 + jt * 64 + col] = bz;
  }
#pragma unroll
  for (int h = 0; h < 2; h++) {
    int vi = tid + h * 256;
    int b = vi >> 6, d0 = vi & 63;
    const float* p = part3 + (size_t)b * 64 * 512 + kt * 64 + d0;
    float e = 0.f;
#pragma unroll 8
    for (int j = 0; j < 64; j++) e += p[j * 512];
    emb_s[vi] = e * (1.0f / TOPK_K);
  }
  __syncthreads();
  float a0 = 0.f, a1 = 0.f;
  const float* wrow = pW1 + (size_t)(kt * 64) * 512 + jt * 64 + col;
#pragma unroll 8
  for (int q = 0; q < 64; q++) {
    float wq = wrow[q * 512];
    a0 += emb_s[(bg * 2) * 64 + q] * wq;
    a1 += emb_s[(bg * 2 + 1) * 64 + q] * wq;
  }
  part1[kt * 4096 + (bg * 2) * 512 + jt * 64 + col] = a0;
  part1[kt * 4096 + (bg * 2 + 1) * 512 + jt * 64 + col] = a1;
}

__global__ __launch_bounds__(256) void k_proj2(const float* __restrict__ part1,
                                               const float* __restrict__ pb1,
                                               const float* __restrict__ pW2,
                                               float* __restrict__ out) {
  int jt = blockIdx.x & 7, kt = blockIdx.x >> 3;
  __shared__ float h_s[512];
  int tid = threadIdx.x;
#pragma unroll
  for (int h = 0; h < 2; h++) {
    int vi = tid + h * 256;
    int b = vi >> 6, j0 = vi & 63;
    int jj = kt * 64 + j0;
    float s = pb1[jj];
#pragma unroll
    for (int p = 0; p < 8; p++) s += part1[p * 4096 + b * 512 + jj];
    h_s[vi] = gelu_f(s);
  }
  __syncthreads();
  int col = tid & 63, bg = tid >> 6;
  float a0 = 0.f, a1 = 0.f;
  const float* wrow = pW2 + (size_t)(kt * 64) * 512 + jt * 64 + col;
#pragma unroll 8
  for (int q = 0; q < 64; q++) {
    float wq = wrow[q * 512];
    a0 += h_s[(bg * 2) * 64 + q] * wq;
    a1 += h_s[(bg * 2 + 1) * 64 + q] * wq;
  }
  atomicAdd(&out[(bg * 2) * 512 + jt * 64 + col], a0);
  atomicAdd(&out[(bg * 2 + 1) * 512 + jt * 64 + col], a1);
}

extern "C" void kernel_launch(void* const* d_in, const int* in_sizes, int n_in,
                              void* d_out, int out_size, void* d_ws, size_t ws_size,
                              hipStream_t stream) {
  (void)in_sizes; (void)n_in; (void)out_size; (void)ws_size;
  const float* x   = (const float*)d_in[0];
  const float* aW1 = (const float*)d_in[1];
  const float* ab1 = (const float*)d_in[2];
  const float* aW2 = (const float*)d_in[3];
  const float* ab2 = (const float*)d_in[4];
  const float* pW1 = (const float*)d_in[5];
  const float* pb1 = (const float*)d_in[6];
  const float* pW2 = (const float*)d_in[7];
  const float* pb2 = (const float*)d_in[8];

  float* out  = (float*)d_out;
  float* wout = out + B_BAGS * D_DIM;  // weights output region [8][8192]

  char* ws = (char*)d_ws;
  unsigned short* w1p_hi = (unsigned short*)(ws + WS_W1P_HI);
  unsigned short* w1p_lo = (unsigned short*)(ws + WS_W1P_LO);
  float* part3 = (float*)(ws + WS_PART3);
  float* part1 = (float*)(ws + WS_PART1);

  k_prep<<<dim3(16), dim3(256), 0, stream>>>(aW1, w1p_hi, w1p_lo);
  k_scores<<<dim3(ROWS_TOTAL / BM), dim3(256), 0, stream>>>(x, w1p_hi, w1p_lo, ab1, aW2, ab2, wout);
  k_gather<<<dim3(B_BAGS * 64), dim3(256), 0, stream>>>(x, wout, part3);
  k_proj1<<<dim3(64), dim3(256), 0, stream>>>(part3, pW1, part1, pb2, out);
  k_proj2<<<dim3(64), dim3(256), 0, stream>>>(part1, pb1, pW2, out);
}